// Round 9
// baseline (381.956 us; speedup 1.0000x reference)
//
#include <hip/hip_runtime.h>
#include <hip/hip_fp16.h>

// CRF NLL, B=256, T=1024, L=64.
// Meet-in-the-middle fwd/bwd chains (round-0 structure: 768 independent waves,
// trivial combine, no matrix segments). Inner step replaced by the MFMA
// formulation validated in rounds 6-7 at absmax 0.0:
//   state alpha = C-tile column set (rows m=16mb+4H+r, col j0; all 16 columns
//   replicated -> wave-uniform renorm, no cross-lane ops),
//   step = renorm (16-reg tree + readfirstlane, exact pow-2)
//        -> 16 mul -> 8 cvt_pkrtz (zero-shuffle C->B repack, KG bijection)
//        -> 8 x mfma_f32_16x16x32_f16 -> 16 E-mul.
// The 64-wide reduction that cost 32 readlane + 32 fdot2 (~455 cyc/step
// latency) becomes one matrix op (~230 cyc/step issue).

typedef _Float16 h2 __attribute__((ext_vector_type(2)));
typedef _Float16 half8 __attribute__((ext_vector_type(8)));
typedef float f32x4 __attribute__((ext_vector_type(4)));
typedef unsigned u32x4 __attribute__((ext_vector_type(4)));

#define B2U(x) __builtin_bit_cast(unsigned, x)
#define L2E 1.44269504088896340736f
#define LN2 0.69314718055994530942f
#define EXPE(p) __builtin_amdgcn_exp2f((p) * L2E)
#define MF32(a, b, c) __builtin_amdgcn_mfma_f32_16x16x32_f16(a, b, c, 0, 0, 0)

// slot->k bijection within a 32-k slice (validated rounds 6-7):
// e<4 -> 32ks+4H+e ; e>=4 -> 32ks+16+4H+(e-4)
#define KG(ks, H, e) (32*(ks) + (((e) < 4) ? (4*(H) + (e)) : (16 + 4*(H) + (e) - 4)))

template<bool FWD>
__device__ __forceinline__ void chainM(const float* __restrict__ pred,
                                       const float* __restrict__ trans,
                                       int b, int lane, int sl, int h,
                                       float* __restrict__ wsV,
                                       int* __restrict__ wsK)
{
    const int H  = lane >> 4;    // 0..3
    const int j0 = lane & 15;
    const f32x4 Z4 = {0.f, 0.f, 0.f, 0.f};
    const float* pb = pred + (size_t)b * 65536;

    // A basis. fwd: A[m][k] = exp(trans[k][m]) (A = V^T, alpha' = diag(E) V^T alpha)
    //          bwd: A[m][k] = exp(trans[m][k]) (A = V,   beta'  = V (E . beta))
    half8 VA[4][2];
    #pragma unroll
    for (int mb = 0; mb < 4; ++mb)
        #pragma unroll
        for (int ks = 0; ks < 2; ++ks) {
            u32x4 q;
            if (FWD) {
                const float* tp = trans + 16*mb + j0;
                q.x = B2U(__builtin_amdgcn_cvt_pkrtz(EXPE(tp[KG(ks,H,0)*66]), EXPE(tp[KG(ks,H,1)*66])));
                q.y = B2U(__builtin_amdgcn_cvt_pkrtz(EXPE(tp[KG(ks,H,2)*66]), EXPE(tp[KG(ks,H,3)*66])));
                q.z = B2U(__builtin_amdgcn_cvt_pkrtz(EXPE(tp[KG(ks,H,4)*66]), EXPE(tp[KG(ks,H,5)*66])));
                q.w = B2U(__builtin_amdgcn_cvt_pkrtz(EXPE(tp[KG(ks,H,6)*66]), EXPE(tp[KG(ks,H,7)*66])));
            } else {
                const float* tp = trans + (16*mb + j0) * 66;
                q.x = B2U(__builtin_amdgcn_cvt_pkrtz(EXPE(tp[KG(ks,H,0)]), EXPE(tp[KG(ks,H,1)])));
                q.y = B2U(__builtin_amdgcn_cvt_pkrtz(EXPE(tp[KG(ks,H,2)]), EXPE(tp[KG(ks,H,3)])));
                q.z = B2U(__builtin_amdgcn_cvt_pkrtz(EXPE(tp[KG(ks,H,4)]), EXPE(tp[KG(ks,H,5)])));
                q.w = B2U(__builtin_amdgcn_cvt_pkrtz(EXPE(tp[KG(ks,H,6)]), EXPE(tp[KG(ks,H,7)])));
            }
            VA[mb][ks] = __builtin_bit_cast(half8, q);
        }

    // C init: per-lane rows m = 16mb+4H+r (all columns replicated).
    f32x4 C[4];
    #pragma unroll
    for (int a = 0; a < 4; ++a)
        #pragma unroll
        for (int r = 0; r < 4; ++r) {
            int m = 16*a + 4*H + r;
            C[a][r] = FWD ? EXPE(pb[m] + trans[64*66 + m])
                          : EXPE(trans[m*66 + 65]);
        }

    int K = 0;
    int n = FWD ? h - 1 : sl - h;
    int t = FWD ? 1 : sl - 1;
    const int dir = FWD ? 1 : -1;

    // PE[a] = pred[t][16a+4H .. +3] — same address set both directions.
    const float* pt = pb + (size_t)t * 64 + 4*H;
    f32x4 PE[4] = { *(const f32x4*)(pt +  0), *(const f32x4*)(pt + 16),
                    *(const f32x4*)(pt + 32), *(const f32x4*)(pt + 48) };

    while (n > 0) {
        // prefetch next step's pred row (always in [0,1023])
        const float* pn = pb + (size_t)(t + dir) * 64 + 4*H;
        f32x4 P0 = *(const f32x4*)(pn +  0), P1 = *(const f32x4*)(pn + 16),
              P2 = *(const f32x4*)(pn + 32), P3 = *(const f32x4*)(pn + 48);

        // E = exp(pred[t]) — off the C critical path (PE ready from last iter)
        f32x4 EX[4];
        #pragma unroll
        for (int a = 0; a < 4; ++a) {
            EX[a][0] = EXPE(PE[a][0]); EX[a][1] = EXPE(PE[a][1]);
            EX[a][2] = EXPE(PE[a][2]); EX[a][3] = EXPE(PE[a][3]);
        }

        // exact pow-2 renorm (ref = 16-row subset sum at lane 0, as midseg)
        float sr = ((C[0][0]+C[0][1])+(C[0][2]+C[0][3]))
                 + ((C[1][0]+C[1][1])+(C[1][2]+C[1][3]))
                 + ((C[2][0]+C[2][1])+(C[2][2]+C[2][3]))
                 + ((C[3][0]+C[3][1])+(C[3][2]+C[3][3]));
        unsigned cb = (unsigned)__builtin_amdgcn_readfirstlane((int)__float_as_uint(sr));
        int kk = (int)((cb >> 23) & 255u) - 129;   // ilogb(sr) - 2
        K += kk;
        float sc = __uint_as_float((unsigned)(127 - kk) << 23);

        // B operand: fwd Tv = C*sc ; bwd Tv = C*(E*sc) (E on input rows k=m)
        f32x4 Tv[4];
        #pragma unroll
        for (int a = 0; a < 4; ++a) {
            if (FWD) {
                Tv[a][0]=C[a][0]*sc; Tv[a][1]=C[a][1]*sc;
                Tv[a][2]=C[a][2]*sc; Tv[a][3]=C[a][3]*sc;
            } else {
                Tv[a][0]=C[a][0]*(EX[a][0]*sc); Tv[a][1]=C[a][1]*(EX[a][1]*sc);
                Tv[a][2]=C[a][2]*(EX[a][2]*sc); Tv[a][3]=C[a][3]*(EX[a][3]*sc);
            }
        }
        // zero-shuffle repack: Bf[ks] = concat(cvt4(Tv[2ks]), cvt4(Tv[2ks+1]))
        u32x4 qb0, qb1;
        qb0.x = B2U(__builtin_amdgcn_cvt_pkrtz(Tv[0][0], Tv[0][1]));
        qb0.y = B2U(__builtin_amdgcn_cvt_pkrtz(Tv[0][2], Tv[0][3]));
        qb0.z = B2U(__builtin_amdgcn_cvt_pkrtz(Tv[1][0], Tv[1][1]));
        qb0.w = B2U(__builtin_amdgcn_cvt_pkrtz(Tv[1][2], Tv[1][3]));
        qb1.x = B2U(__builtin_amdgcn_cvt_pkrtz(Tv[2][0], Tv[2][1]));
        qb1.y = B2U(__builtin_amdgcn_cvt_pkrtz(Tv[2][2], Tv[2][3]));
        qb1.z = B2U(__builtin_amdgcn_cvt_pkrtz(Tv[3][0], Tv[3][1]));
        qb1.w = B2U(__builtin_amdgcn_cvt_pkrtz(Tv[3][2], Tv[3][3]));
        half8 Bf0 = __builtin_bit_cast(half8, qb0);
        half8 Bf1 = __builtin_bit_cast(half8, qb1);

        // 8 MFMAs; fwd post-scales output rows by E (alpha = E . (V^T x))
        #pragma unroll
        for (int mb = 0; mb < 4; ++mb) {
            f32x4 acc = MF32(VA[mb][0], Bf0, Z4);
            acc = MF32(VA[mb][1], Bf1, acc);
            if (FWD) {
                C[mb][0] = acc[0]*EX[mb][0]; C[mb][1] = acc[1]*EX[mb][1];
                C[mb][2] = acc[2]*EX[mb][2]; C[mb][3] = acc[3]*EX[mb][3];
            } else {
                C[mb] = acc;
            }
        }

        PE[0] = P0; PE[1] = P1; PE[2] = P2; PE[3] = P3;
        t += dir; --n;
    }

    // store state vector (column 0; all columns replicated, gate on j0==0)
    if (j0 == 0) {
        #pragma unroll
        for (int mb = 0; mb < 4; ++mb)
            *(f32x4*)(wsV + b * 64 + 16*mb + 4*H) = C[mb];
    }
    if (lane == 0) wsK[b] = K;
}

__global__ __launch_bounds__(64) __attribute__((amdgpu_waves_per_eu(1, 1)))
void chain_kernel(const float* __restrict__ pred,
                  const float* __restrict__ trans,
                  const int*   __restrict__ ref,
                  const int*   __restrict__ seqlen,
                  float* __restrict__ wsA, float* __restrict__ wsB,
                  int* __restrict__ wsKf, int* __restrict__ wsKb,
                  float* __restrict__ out)
{
    const int role = blockIdx.x >> 8;
    const int b    = blockIdx.x & 255;
    const int lane = threadIdx.x;
    const int sl   = seqlen[b];
    const int h    = (sl + 1) >> 1;

    if (role == 0) {
        chainM<true>(pred, trans, b, lane, sl, h, wsA, wsKf);
    } else if (role == 1) {
        chainM<false>(pred, trans, b, lane, sl, h, wsB, wsKb);
    } else {
        // gold-path score (verified round 0)
        const int*   rb = ref  + b * 1024;
        const float* pg = pred + (size_t)b * 65536;
        float acc = 0.f;
        for (int t = lane; t <= sl; t += 64) {
            int from = (t == 0) ? 64 : rb[t - 1];
            int cur  = (t < sl) ? rb[t] : 65;
            acc += trans[from * 66 + cur];
            if (t < sl) acc += pg[t * 64 + cur];
        }
        #pragma unroll
        for (int off = 32; off; off >>= 1) acc += __shfl_xor(acc, off, 64);
        if (lane == 0) atomicAdd(out, -acc);
    }
}

__global__ __launch_bounds__(64) void combine_kernel(
    const float* __restrict__ wsA, const float* __restrict__ wsB,
    const int* __restrict__ wsKf, const int* __restrict__ wsKb,
    float* __restrict__ out)
{
    const int b = blockIdx.x, lane = threadIdx.x;
    float z = wsA[b * 64 + lane] * wsB[b * 64 + lane];
    #pragma unroll
    for (int off = 32; off; off >>= 1) z += __shfl_xor(z, off, 64);
    if (lane == 0) {
        float res = LN2 * (__builtin_amdgcn_logf(z) + (float)(wsKf[b] + wsKb[b]));
        atomicAdd(out, res);
    }
}

extern "C" void kernel_launch(void* const* d_in, const int* in_sizes, int n_in,
                              void* d_out, int out_size, void* d_ws, size_t ws_size,
                              hipStream_t stream) {
    const float* pred   = (const float*)d_in[0];
    const float* trans  = (const float*)d_in[1];
    const int*   ref    = (const int*)d_in[2];
    const int*   seqlen = (const int*)d_in[3];
    float* out = (float*)d_out;

    float* wsA  = (float*)d_ws;            // 256*64 f32
    float* wsB  = wsA + 256 * 64;          // 256*64 f32
    int*   wsKf = (int*)(wsB + 256 * 64);  // 256 i32
    int*   wsKb = wsKf + 256;              // 256 i32

    hipMemsetAsync(out, 0, sizeof(float), stream);
    chain_kernel<<<768, 64, 0, stream>>>(pred, trans, ref, seqlen,
                                         wsA, wsB, wsKf, wsKb, out);
    combine_kernel<<<256, 64, 0, stream>>>(wsA, wsB, wsKf, wsKb, out);
}